// Round 1
// baseline (479.640 us; speedup 1.0000x reference)
//
#include <hip/hip_runtime.h>

#define H 32
#define GROUPS_PER_BLOCK 8   // 256 threads / 32 lanes

// tanh(x) = 1 - 2/(1 + exp(2x)); exp(2x) = exp2(x * 2*log2(e))
// Saturates correctly: x -> +inf: exp2 -> inf, rcp -> 0, result 1.
//                      x -> -inf: exp2 -> 0,  result 1 - 2 = -1.
__device__ __forceinline__ float fast_tanh(float x) {
    float e = __builtin_amdgcn_exp2f(x * 2.8853900817779268f); // 2*log2(e)
    float r = __builtin_amdgcn_rcpf(e + 1.0f);
    return fmaf(-2.0f, r, 1.0f);
}

__global__ __launch_bounds__(256, 1) void rnn_fused(
    const float* __restrict__ onehot,   // [B,T,4]
    const float* __restrict__ rewards,  // [B,T,1]
    const float* __restrict__ W_ih,     // [H,5]
    const float* __restrict__ W_hh,     // [H,H]
    const float* __restrict__ b_ih,     // [H]
    const float* __restrict__ b_hh,     // [H]
    const float* __restrict__ W_ro,     // [4,H]
    const float* __restrict__ b_ro,     // [4]
    float* __restrict__ out_logits,     // [B,T,4]
    float* __restrict__ out_hT,         // [B,H]
    int T)
{
    const int tid = threadIdx.x;
    const int j = tid & 31;                  // hidden unit owned by this lane
    const int g = tid >> 5;                  // group (batch element) in block
    const int b = blockIdx.x * GROUPS_PER_BLOCK + g;

    // 36-float pitch = 144 B per group: 16B-aligned for b128 reads, and the
    // two groups of a wave land on disjoint bank sets (offset 4 banks).
    __shared__ __align__(16) float hx[GROUPS_PER_BLOCK][36];

    // ---- persistent per-lane weights ----
    float whh[H];
#pragma unroll
    for (int k = 0; k < 8; ++k) {
        float4 w = *(const float4*)(W_hh + j * H + k * 4);
        whh[4 * k + 0] = w.x; whh[4 * k + 1] = w.y;
        whh[4 * k + 2] = w.z; whh[4 * k + 3] = w.w;
    }
    const int a = j & 3;                     // readout row this lane computes
    float wro[H];
#pragma unroll
    for (int k = 0; k < 8; ++k) {
        float4 w = *(const float4*)(W_ro + a * H + k * 4);
        wro[4 * k + 0] = w.x; wro[4 * k + 1] = w.y;
        wro[4 * k + 2] = w.z; wro[4 * k + 3] = w.w;
    }
    const float wih0 = W_ih[j * 5 + 0];
    const float wih1 = W_ih[j * 5 + 1];
    const float wih2 = W_ih[j * 5 + 2];
    const float wih3 = W_ih[j * 5 + 3];
    const float wih4 = W_ih[j * 5 + 4];
    const float bias = b_ih[j] + b_hh[j];    // reference folds both into x_proj
    const float bro  = b_ro[a];

    const float* oh_ptr = onehot  + (size_t)b * T * 4;
    const float* rw_ptr = rewards + (size_t)b * T;
    float*       lg_ptr = out_logits + (size_t)b * T * 4;

    // prefetch x for t = 0
    float4 x4 = *(const float4*)(oh_ptr);
    float  xr = rw_ptr[0];

    float hj = 0.0f;                         // h_{-1} = 0

    for (int t = 0; t < T; ++t) {
        // input projection for step t (uses prefetched x)
        float xp = bias;
        xp = fmaf(x4.x, wih0, xp);
        xp = fmaf(x4.y, wih1, xp);
        xp = fmaf(x4.z, wih2, xp);
        xp = fmaf(x4.w, wih3, xp);
        xp = fmaf(xr,  wih4, xp);

        // prefetch x for t+1 (independent of everything below)
        if (t + 1 < T) {
            x4 = *(const float4*)(oh_ptr + (size_t)(t + 1) * 4);
            xr = rw_ptr[t + 1];
        }

        // wave-synchronous exchange of h_{t-1}: write own, gather all 32
        hx[g][j] = hj;
        float hp[H];
#pragma unroll
        for (int k = 0; k < 8; ++k) {
            float4 v = *(const float4*)(&hx[g][4 * k]);
            hp[4 * k + 0] = v.x; hp[4 * k + 1] = v.y;
            hp[4 * k + 2] = v.z; hp[4 * k + 3] = v.w;
        }

        // readout for step t-1 (lagged: uses gathered h_{t-1})
        if (t > 0) {
            float l0 = 0.f, l1 = 0.f, l2 = 0.f, l3 = 0.f;
#pragma unroll
            for (int k = 0; k < 8; ++k) {
                l0 = fmaf(hp[4 * k + 0], wro[4 * k + 0], l0);
                l1 = fmaf(hp[4 * k + 1], wro[4 * k + 1], l1);
                l2 = fmaf(hp[4 * k + 2], wro[4 * k + 2], l2);
                l3 = fmaf(hp[4 * k + 3], wro[4 * k + 3], l3);
            }
            float lg = ((l0 + l1) + (l2 + l3)) + bro;
            if (j < 4) lg_ptr[(size_t)(t - 1) * 4 + j] = lg;
        }

        // recurrence: h_t = tanh(xp_t + W_hh @ h_{t-1})
        float a0 = xp, a1 = 0.f, a2 = 0.f, a3 = 0.f;
#pragma unroll
        for (int k = 0; k < 8; ++k) {
            a0 = fmaf(hp[4 * k + 0], whh[4 * k + 0], a0);
            a1 = fmaf(hp[4 * k + 1], whh[4 * k + 1], a1);
            a2 = fmaf(hp[4 * k + 2], whh[4 * k + 2], a2);
            a3 = fmaf(hp[4 * k + 3], whh[4 * k + 3], a3);
        }
        hj = fast_tanh((a0 + a1) + (a2 + a3));
    }

    // final exchange: readout for t = T-1, plus h_T
    hx[g][j] = hj;
    float hp[H];
#pragma unroll
    for (int k = 0; k < 8; ++k) {
        float4 v = *(const float4*)(&hx[g][4 * k]);
        hp[4 * k + 0] = v.x; hp[4 * k + 1] = v.y;
        hp[4 * k + 2] = v.z; hp[4 * k + 3] = v.w;
    }
    float l0 = 0.f, l1 = 0.f, l2 = 0.f, l3 = 0.f;
#pragma unroll
    for (int k = 0; k < 8; ++k) {
        l0 = fmaf(hp[4 * k + 0], wro[4 * k + 0], l0);
        l1 = fmaf(hp[4 * k + 1], wro[4 * k + 1], l1);
        l2 = fmaf(hp[4 * k + 2], wro[4 * k + 2], l2);
        l3 = fmaf(hp[4 * k + 3], wro[4 * k + 3], l3);
    }
    float lg = ((l0 + l1) + (l2 + l3)) + bro;
    if (j < 4) lg_ptr[(size_t)(T - 1) * 4 + j] = lg;

    out_hT[(size_t)b * H + j] = hj;
}

extern "C" void kernel_launch(void* const* d_in, const int* in_sizes, int n_in,
                              void* d_out, int out_size, void* d_ws, size_t ws_size,
                              hipStream_t stream) {
    const float* onehot  = (const float*)d_in[0];
    const float* rewards = (const float*)d_in[1];
    const float* W_ih    = (const float*)d_in[2];
    const float* W_hh    = (const float*)d_in[3];
    const float* b_ih    = (const float*)d_in[4];
    const float* b_hh    = (const float*)d_in[5];
    const float* W_ro    = (const float*)d_in[6];
    const float* b_ro    = (const float*)d_in[7];

    const int T = 1024;                      // per setup_inputs()
    const int B = in_sizes[1] / T;           // in_sizes[1] = B*T

    float* out_logits = (float*)d_out;                        // [B,T,4]
    float* out_hT     = (float*)d_out + (size_t)B * T * 4;    // [B,H]

    dim3 block(256);
    dim3 grid(B / GROUPS_PER_BLOCK);
    rnn_fused<<<grid, block, 0, stream>>>(onehot, rewards, W_ih, W_hh,
                                          b_ih, b_hh, W_ro, b_ro,
                                          out_logits, out_hT, T);
}

// Round 2
// 362.251 us; speedup vs baseline: 1.3241x; 1.3241x over previous
//
#include <hip/hip_runtime.h>

#define H 32
#define GPB 8   // 32-lane groups per 256-thread block

// tanh(x) = 1 - 2/(1 + exp2(x * 2*log2(e))); saturates correctly at +/-inf.
__device__ __forceinline__ float fast_tanh(float x) {
    float e = __builtin_amdgcn_exp2f(x * 2.8853900817779268f);
    float r = __builtin_amdgcn_rcpf(e + 1.0f);
    return fmaf(-2.0f, r, 1.0f);
}

__global__ __launch_bounds__(256, 1) void rnn_fused(
    const float* __restrict__ onehot,   // [B,T,4]
    const float* __restrict__ rewards,  // [B,T]
    const float* __restrict__ W_ih,     // [H,5]
    const float* __restrict__ W_hh,     // [H,H]
    const float* __restrict__ b_ih,     // [H]
    const float* __restrict__ b_hh,     // [H]
    const float* __restrict__ W_ro,     // [4,H]
    const float* __restrict__ b_ro,     // [4]
    float* __restrict__ out_logits,     // [B,T,4]
    float* __restrict__ out_hT,         // [B,H]
    int T)
{
    const int tid = threadIdx.x;
    const int j = tid & 31;                  // hidden unit owned by this lane
    const int g = tid >> 5;                  // group (batch element) in block
    const int b = blockIdx.x * GPB + g;

    // 36-float pitch (144B): 16B-aligned bases, wave's two groups on
    // disjoint bank quads. Wave-synchronous (no barriers needed).
    __shared__ __align__(16) float hx[GPB][36];

    // ---- persistent per-lane weights ----
    float whh[H];
#pragma unroll
    for (int k = 0; k < 8; ++k) {
        float4 w = *(const float4*)(W_hh + j * H + 4 * k);
        whh[4*k+0] = w.x; whh[4*k+1] = w.y; whh[4*k+2] = w.z; whh[4*k+3] = w.w;
    }
    const int a = j & 3;                     // readout row this lane computes
    float wro[H];
#pragma unroll
    for (int k = 0; k < 8; ++k) {
        float4 w = *(const float4*)(W_ro + a * H + 4 * k);
        wro[4*k+0] = w.x; wro[4*k+1] = w.y; wro[4*k+2] = w.z; wro[4*k+3] = w.w;
    }
    const float wih0 = W_ih[j*5+0], wih1 = W_ih[j*5+1], wih2 = W_ih[j*5+2],
                wih3 = W_ih[j*5+3], wih4 = W_ih[j*5+4];
    const float bias = b_ih[j] + b_hh[j];
    const float bro  = b_ro[a];

    const float* oh_ptr = onehot  + (size_t)b * T * 4;
    const float* rw_ptr = rewards + (size_t)b * T;
    float*       lg_ptr = out_logits + (size_t)b * T * 4;

    // ---- 4-step-deep x prefetch ring (covers HBM latency) ----
    float4 oh0 = *(const float4*)(oh_ptr + 0);
    float4 oh1 = *(const float4*)(oh_ptr + 4);
    float4 oh2 = *(const float4*)(oh_ptr + 8);
    float4 oh3 = *(const float4*)(oh_ptr + 12);
    float4 rw  = *(const float4*)(rw_ptr);

    float hj = 0.0f;                         // h_{-1} = 0
    float hA[H], hB[H];                      // ping-pong gathered-h buffers

    // readout of step t from gathered values hv (= h_t)
    auto readout = [&](const float (&hv)[H], int t) {
        float l0 = 0.f, l1 = 0.f, l2 = 0.f, l3 = 0.f;
#pragma unroll
        for (int k = 0; k < 8; ++k) {
            l0 = fmaf(hv[4*k+0], wro[4*k+0], l0);
            l1 = fmaf(hv[4*k+1], wro[4*k+1], l1);
            l2 = fmaf(hv[4*k+2], wro[4*k+2], l2);
            l3 = fmaf(hv[4*k+3], wro[4*k+3], l3);
        }
        float lg = ((l0 + l1) + (l2 + l3)) + bro;
        if (j < 4) lg_ptr[(size_t)t * 4 + j] = lg;
    };

    // one recurrence step: gathers h_{t-1} into cur, emits logits(t-2) from
    // prv while the ds_reads are in flight, then h_t = tanh(xp + Whh h_{t-1})
    auto step = [&](float (&cur)[H], const float (&prv)[H], float xp, int t) {
        hx[g][j] = hj;                       // publish h_{t-1}
#pragma unroll
        for (int k = 0; k < 8; ++k) {
            float4 v = *(const float4*)(&hx[g][4 * k]);
            cur[4*k+0] = v.x; cur[4*k+1] = v.y;
            cur[4*k+2] = v.z; cur[4*k+3] = v.w;
        }
        if (t >= 2) readout(prv, t - 2);     // latency filler (no lgkm dep)
        float a0 = xp, a1 = 0.f, a2 = 0.f, a3 = 0.f;
#pragma unroll
        for (int k = 0; k < 8; ++k) {
            a0 = fmaf(cur[4*k+0], whh[4*k+0], a0);
            a1 = fmaf(cur[4*k+1], whh[4*k+1], a1);
            a2 = fmaf(cur[4*k+2], whh[4*k+2], a2);
            a3 = fmaf(cur[4*k+3], whh[4*k+3], a3);
        }
        hj = fast_tanh((a0 + a1) + (a2 + a3));
    };

    for (int tb = 0; tb < T; tb += 4) {
        // consume x for steps tb..tb+3 (loads were issued one block ago)
        float xp0 = fmaf(oh0.x,wih0, fmaf(oh0.y,wih1, fmaf(oh0.z,wih2, fmaf(oh0.w,wih3, fmaf(rw.x,wih4, bias)))));
        float xp1 = fmaf(oh1.x,wih0, fmaf(oh1.y,wih1, fmaf(oh1.z,wih2, fmaf(oh1.w,wih3, fmaf(rw.y,wih4, bias)))));
        float xp2 = fmaf(oh2.x,wih0, fmaf(oh2.y,wih1, fmaf(oh2.z,wih2, fmaf(oh2.w,wih3, fmaf(rw.z,wih4, bias)))));
        float xp3 = fmaf(oh3.x,wih0, fmaf(oh3.y,wih1, fmaf(oh3.z,wih2, fmaf(oh3.w,wih3, fmaf(rw.w,wih4, bias)))));

        // issue loads for steps tb+4..tb+7 (consumed next block, ~700+cy away)
        if (tb + 4 < T) {
            oh0 = *(const float4*)(oh_ptr + (size_t)(tb + 4) * 4);
            oh1 = *(const float4*)(oh_ptr + (size_t)(tb + 5) * 4);
            oh2 = *(const float4*)(oh_ptr + (size_t)(tb + 6) * 4);
            oh3 = *(const float4*)(oh_ptr + (size_t)(tb + 7) * 4);
            rw  = *(const float4*)(rw_ptr + tb + 4);
        }

        step(hA, hB, xp0, tb + 0);
        step(hB, hA, xp1, tb + 1);
        step(hA, hB, xp2, tb + 2);
        step(hB, hA, xp3, tb + 3);
    }

    // epilogue:
    // last step (t=T-1) gathered h_{T-2} into hB; logits(T-3) was last emitted.
    readout(hB, T - 2);                      // logits(T-2) from h_{T-2}
    hx[g][j] = hj;                           // publish h_{T-1}
#pragma unroll
    for (int k = 0; k < 8; ++k) {
        float4 v = *(const float4*)(&hx[g][4 * k]);
        hA[4*k+0] = v.x; hA[4*k+1] = v.y; hA[4*k+2] = v.z; hA[4*k+3] = v.w;
    }
    readout(hA, T - 1);                      // logits(T-1) from h_{T-1}
    out_hT[(size_t)b * H + j] = hj;          // h_T (final hidden state)
}

extern "C" void kernel_launch(void* const* d_in, const int* in_sizes, int n_in,
                              void* d_out, int out_size, void* d_ws, size_t ws_size,
                              hipStream_t stream) {
    const float* onehot  = (const float*)d_in[0];
    const float* rewards = (const float*)d_in[1];
    const float* W_ih    = (const float*)d_in[2];
    const float* W_hh    = (const float*)d_in[3];
    const float* b_ih    = (const float*)d_in[4];
    const float* b_hh    = (const float*)d_in[5];
    const float* W_ro    = (const float*)d_in[6];
    const float* b_ro    = (const float*)d_in[7];

    const int T = 1024;                      // per setup_inputs()
    const int B = in_sizes[1] / T;           // in_sizes[1] = B*T

    float* out_logits = (float*)d_out;                        // [B,T,4]
    float* out_hT     = (float*)d_out + (size_t)B * T * 4;    // [B,H]

    dim3 block(256);
    dim3 grid(B / GPB);
    rnn_fused<<<grid, block, 0, stream>>>(onehot, rewards, W_ih, W_hh,
                                          b_ih, b_hh, W_ro, b_ro,
                                          out_logits, out_hT, T);
}

// Round 3
// 322.161 us; speedup vs baseline: 1.4888x; 1.1244x over previous
//
#include <hip/hip_runtime.h>

#define H 32
#define GPB 8      // 32-lane groups per 256-thread block
#define PITCH 48   // floats per LDS group (192 B): wave's 2 groups alias <=2-way (free)

// tanh(x) = 1 - 2/(1 + exp2(x * 2*log2(e))); saturates correctly at +/-inf.
__device__ __forceinline__ float fast_tanh(float x) {
    float e = __builtin_amdgcn_exp2f(x * 2.8853900817779268f);
    float r = __builtin_amdgcn_rcpf(e + 1.0f);
    return fmaf(-2.0f, r, 1.0f);
}

// acc += (quad-lane q's copy of p) * w  — one v_fmac_f32_dpp.
// p regs are only ever written by ds_read (lgkmcnt-guarded), so no VALU->DPP hazard.
#define QFMA(acc, p, w, q) \
    asm("v_fmac_f32_dpp %0, %1, %2 quad_perm:[" #q "," #q "," #q "," #q "] row_mask:0xf bank_mask:0xf" \
        : "+v"(acc) : "v"(p), "v"(w))

// 8-FMA chain for k in [8q, 8q+8): weights whh[8q+i], h values from quad-lane q
#define CH8(acc, q) \
    QFMA(acc, pN[0], whh[8*q+0], q); QFMA(acc, pN[1], whh[8*q+1], q); \
    QFMA(acc, pN[2], whh[8*q+2], q); QFMA(acc, pN[3], whh[8*q+3], q); \
    QFMA(acc, pN[4], whh[8*q+4], q); QFMA(acc, pN[5], whh[8*q+5], q); \
    QFMA(acc, pN[6], whh[8*q+6], q); QFMA(acc, pN[7], whh[8*q+7], q)

// dpp mov with bound_ctrl: invalid lanes contribute 0 (safe for shift-reduce)
#define DPPMOV(x, ctrl) \
    __int_as_float(__builtin_amdgcn_update_dpp(0, __float_as_int(x), (ctrl), 0xf, 0xf, true))
#define ROW_SHR1 0x111
#define ROW_SHR2 0x112
#define ROW_SHR4 0x114

__global__ __launch_bounds__(256, 1) void rnn_fused(
    const float* __restrict__ onehot,   // [B,T,4]
    const float* __restrict__ rewards,  // [B,T]
    const float* __restrict__ W_ih,     // [H,5]
    const float* __restrict__ W_hh,     // [H,H]
    const float* __restrict__ b_ih,     // [H]
    const float* __restrict__ b_hh,     // [H]
    const float* __restrict__ W_ro,     // [4,H]
    const float* __restrict__ b_ro,     // [4]
    float* __restrict__ out_logits,     // [B,T,4]
    float* __restrict__ out_hT,         // [B,H]
    int T)
{
    const int tid = threadIdx.x;
    const int j   = tid & 31;            // hidden unit owned by this lane
    const int g   = tid >> 5;            // group (batch element) in block
    const int b   = blockIdx.x * GPB + g;
    const int qp  = j & 3;               // quad position -> which 8-chunk we hold
    const int r   = j >> 3;              // readout row this lane contributes to
    const bool hi = ((j >> 2) & 1) != 0; // which half of our chunk for readout
    const bool writer = (j & 7) == 7;    // lane that stores logit row r

    __shared__ __align__(16) float hx[GPB * PITCH];
    float* lds_wr = &hx[g * PITCH + j];
    const float4* lds_rd0 = (const float4*)&hx[g * PITCH + qp * 8];
    const float4* lds_rd1 = lds_rd0 + 1;

    // ---- persistent per-lane weights ----
    float whh[H];
#pragma unroll
    for (int k = 0; k < 8; ++k) {
        float4 w = *(const float4*)(W_hh + j * H + 4 * k);
        whh[4*k+0] = w.x; whh[4*k+1] = w.y; whh[4*k+2] = w.z; whh[4*k+3] = w.w;
    }
    const float wih0 = W_ih[j*5+0], wih1 = W_ih[j*5+1], wih2 = W_ih[j*5+2],
                wih3 = W_ih[j*5+3], wih4 = W_ih[j*5+4];
    const float bias = b_ih[j] + b_hh[j];
    // readout slice: W_ro[r][8*qp + 4*hi .. +4)  (16B-aligned)
    const float4 wr4 = *(const float4*)(W_ro + r * H + qp * 8 + (hi ? 4 : 0));
    const float bro = b_ro[r];

    const float* oh_ptr = onehot  + (size_t)b * T * 4;
    const float* rw_ptr = rewards + (size_t)b * T;
    float*       lg_ptr = out_logits + (size_t)b * T * 4;

    // ---- 4-step-deep x prefetch ring ----
    float4 oh0 = *(const float4*)(oh_ptr + 0);
    float4 oh1 = *(const float4*)(oh_ptr + 4);
    float4 oh2 = *(const float4*)(oh_ptr + 8);
    float4 oh3 = *(const float4*)(oh_ptr + 12);
    float4 rw  = *(const float4*)(rw_ptr);

    float hj = 0.0f;                     // h^{(-1)} = 0
    float pA[8], pB[8];                  // double-buffered gathered chunk

    // logits_t from a gathered h^{(t)} chunk buffer
    auto readout = [&](const float (&p)[8], int t) {
        float s0 = hi ? p[4] : p[0];
        float s1 = hi ? p[5] : p[1];
        float s2 = hi ? p[6] : p[2];
        float s3 = hi ? p[7] : p[3];
        float s = fmaf(s3, wr4.w, fmaf(s2, wr4.z, fmaf(s1, wr4.y, s0 * wr4.x)));
        s += DPPMOV(s, ROW_SHR1);
        s += DPPMOV(s, ROW_SHR2);
        s += DPPMOV(s, ROW_SHR4);        // lane (8r+7) holds full dot of row r
        if (writer) lg_ptr[(size_t)t * 4 + r] = s + bro;
    };

    // iter t: publish h^{(t-1)}, gather chunk into pN, emit logits_{t-2} from pO
    // (gathered at t-1 = h^{(t-2)}) while reads fly, then h^{(t)} = tanh(xp + Whh h).
    auto step = [&](float (&pN)[8], const float (&pO)[8], float xp, int t, bool ro) {
        *lds_wr = hj;
        float4 v0 = *lds_rd0;
        float4 v1 = *lds_rd1;
        pN[0]=v0.x; pN[1]=v0.y; pN[2]=v0.z; pN[3]=v0.w;
        pN[4]=v1.x; pN[5]=v1.y; pN[6]=v1.z; pN[7]=v1.w;
        if (ro) readout(pO, t - 2);      // latency filler (depends only on pO)
        float a0 = xp, a1 = 0.f, a2 = 0.f, a3 = 0.f;
        CH8(a0, 0);
        CH8(a1, 1);
        CH8(a2, 2);
        CH8(a3, 3);
        hj = fast_tanh((a0 + a1) + (a2 + a3));
    };

    // ---- peeled first block (t = 0..3): no readout for t<2 ----
    {
        float xp0 = fmaf(oh0.x,wih0, fmaf(oh0.y,wih1, fmaf(oh0.z,wih2, fmaf(oh0.w,wih3, fmaf(rw.x,wih4, bias)))));
        float xp1 = fmaf(oh1.x,wih0, fmaf(oh1.y,wih1, fmaf(oh1.z,wih2, fmaf(oh1.w,wih3, fmaf(rw.y,wih4, bias)))));
        float xp2 = fmaf(oh2.x,wih0, fmaf(oh2.y,wih1, fmaf(oh2.z,wih2, fmaf(oh2.w,wih3, fmaf(rw.z,wih4, bias)))));
        float xp3 = fmaf(oh3.x,wih0, fmaf(oh3.y,wih1, fmaf(oh3.z,wih2, fmaf(oh3.w,wih3, fmaf(rw.w,wih4, bias)))));
        oh0 = *(const float4*)(oh_ptr + 16);
        oh1 = *(const float4*)(oh_ptr + 20);
        oh2 = *(const float4*)(oh_ptr + 24);
        oh3 = *(const float4*)(oh_ptr + 28);
        rw  = *(const float4*)(rw_ptr + 4);
        step(pA, pB, xp0, 0, false);
        step(pB, pA, xp1, 1, false);
        step(pA, pB, xp2, 2, true);
        step(pB, pA, xp3, 3, true);
    }

    for (int tb = 4; tb < T; tb += 4) {
        float xp0 = fmaf(oh0.x,wih0, fmaf(oh0.y,wih1, fmaf(oh0.z,wih2, fmaf(oh0.w,wih3, fmaf(rw.x,wih4, bias)))));
        float xp1 = fmaf(oh1.x,wih0, fmaf(oh1.y,wih1, fmaf(oh1.z,wih2, fmaf(oh1.w,wih3, fmaf(rw.y,wih4, bias)))));
        float xp2 = fmaf(oh2.x,wih0, fmaf(oh2.y,wih1, fmaf(oh2.z,wih2, fmaf(oh2.w,wih3, fmaf(rw.z,wih4, bias)))));
        float xp3 = fmaf(oh3.x,wih0, fmaf(oh3.y,wih1, fmaf(oh3.z,wih2, fmaf(oh3.w,wih3, fmaf(rw.w,wih4, bias)))));
        if (tb + 4 < T) {
            oh0 = *(const float4*)(oh_ptr + (size_t)(tb + 4) * 4);
            oh1 = *(const float4*)(oh_ptr + (size_t)(tb + 5) * 4);
            oh2 = *(const float4*)(oh_ptr + (size_t)(tb + 6) * 4);
            oh3 = *(const float4*)(oh_ptr + (size_t)(tb + 7) * 4);
            rw  = *(const float4*)(rw_ptr + tb + 4);
        }
        step(pA, pB, xp0, tb + 0, true);
        step(pB, pA, xp1, tb + 1, true);
        step(pA, pB, xp2, tb + 2, true);
        step(pB, pA, xp3, tb + 3, true);
    }

    // ---- epilogue ----
    readout(pB, T - 2);                  // pB = h^{(T-2)} (gathered at t=T-1)
    *lds_wr = hj;                        // publish h^{(T-1)}
    {
        float4 v0 = *lds_rd0;
        float4 v1 = *lds_rd1;
        pA[0]=v0.x; pA[1]=v0.y; pA[2]=v0.z; pA[3]=v0.w;
        pA[4]=v1.x; pA[5]=v1.y; pA[6]=v1.z; pA[7]=v1.w;
    }
    readout(pA, T - 1);                  // logits_{T-1} from h^{(T-1)}
    out_hT[(size_t)b * H + j] = hj;      // h_T

}

extern "C" void kernel_launch(void* const* d_in, const int* in_sizes, int n_in,
                              void* d_out, int out_size, void* d_ws, size_t ws_size,
                              hipStream_t stream) {
    const float* onehot  = (const float*)d_in[0];
    const float* rewards = (const float*)d_in[1];
    const float* W_ih    = (const float*)d_in[2];
    const float* W_hh    = (const float*)d_in[3];
    const float* b_ih    = (const float*)d_in[4];
    const float* b_hh    = (const float*)d_in[5];
    const float* W_ro    = (const float*)d_in[6];
    const float* b_ro    = (const float*)d_in[7];

    const int T = 1024;                  // per setup_inputs()
    const int B = in_sizes[1] / T;       // in_sizes[1] = B*T

    float* out_logits = (float*)d_out;                        // [B,T,4]
    float* out_hT     = (float*)d_out + (size_t)B * T * 4;    // [B,H]

    dim3 block(256);
    dim3 grid(B / GPB);
    rnn_fused<<<grid, block, 0, stream>>>(onehot, rewards, W_ih, W_hh,
                                          b_ih, b_hh, W_ro, b_ro,
                                          out_logits, out_hT, T);
}